// Round 6
// baseline (99.136 us; speedup 1.0000x reference)
//
#include <hip/hip_runtime.h>

#define NBINS 10001
#define ROWP  10016          // padded row stride in u32 (64B-aligned rows)
#define HIST_BLOCKS 768      // 3 blocks/CU on 256 CUs -> one generation
#define HIST_THREADS 512
#define PCHUNK 128           // partial rows per reduce block
#define RCOLS ((NBINS + 255) / 256)             // 40 bin-chunks
#define RGRID (RCOLS * (HIST_BLOCKS / PCHUNK))  // 240 reduce blocks

typedef unsigned int u32;
typedef unsigned long long u64;
typedef float f4 __attribute__((ext_vector_type(4)));

__device__ __forceinline__ int ks_bin(float x) {
    // sigmoid via v_exp + v_rcp. Edge cases: x<<0 -> e=inf -> rcp(inf)=0 -> b=0;
    // x>>0 -> e=0 -> rcp(1)=1 -> b=10000. s in [0,1] so only upper clamp kept
    // as 1-op insurance against rcp ulp error at the boundary.
    float e = __expf(-x);
    float s = __builtin_amdgcn_rcpf(1.0f + e);
    int b = (int)(10000.0f * s);
    return b > 10000 ? 10000 : b;
}

__device__ __forceinline__ void ks_acc4(u32* lh, f4 p, f4 t) {
#pragma unroll
    for (int k = 0; k < 4; ++k) {
        int b = ks_bin(p[k]);
        u32 add = (t[k] >= 0.5f) ? 0x10000u : 1u;
        atomicAdd(&lh[b], add);
    }
}

// ---------------------------------------------------------------------------
// Kernel 1: per-block LDS histogram (packed u32: tp<<16 | fp).
// Per block at most 45056 elements -> 16-bit packed counts cannot overflow.
// preds: cached loads (L3-resident across replays); targets: nontemporal
// (stream from HBM, skip L1 allocation -> halve L1 miss-slot pressure).
// ---------------------------------------------------------------------------
__global__ __launch_bounds__(HIST_THREADS) void ks_hist(
        const float* __restrict__ preds, const float* __restrict__ tgts,
        u64* __restrict__ ghist, u32* __restrict__ partials,
        int use_partials, int n) {
    __shared__ u32 lh[NBINS];
    for (int i = threadIdx.x; i < NBINS; i += HIST_THREADS) lh[i] = 0u;
    __syncthreads();

    const int n4 = n >> 2;
    const f4* p4 = (const f4*)preds;
    const f4* t4 = (const f4*)tgts;
    const int tid = blockIdx.x * HIST_THREADS + threadIdx.x;
    const int stride = gridDim.x * HIST_THREADS;

    int i = tid;
    for (; i + 3 * stride < n4; i += 4 * stride) {
        f4 p0 = p4[i];
        f4 t0 = __builtin_nontemporal_load(t4 + i);
        f4 p1 = p4[i + stride];
        f4 t1 = __builtin_nontemporal_load(t4 + i + stride);
        f4 p2 = p4[i + 2 * stride];
        f4 t2 = __builtin_nontemporal_load(t4 + i + 2 * stride);
        f4 p3 = p4[i + 3 * stride];
        f4 t3 = __builtin_nontemporal_load(t4 + i + 3 * stride);
        ks_acc4(lh, p0, t0);
        ks_acc4(lh, p1, t1);
        ks_acc4(lh, p2, t2);
        ks_acc4(lh, p3, t3);
    }
    for (; i < n4; i += stride) {
        f4 p = p4[i];
        f4 t = __builtin_nontemporal_load(t4 + i);
        ks_acc4(lh, p, t);
    }

    // scalar tail (n % 4), handled once by block 0
    if (blockIdx.x == 0) {
        int base = n4 << 2;
        int rem = n - base;
        if ((int)threadIdx.x < rem) {
            int j = base + threadIdx.x;
            int b = ks_bin(preds[j]);
            u32 add = (tgts[j] >= 0.5f) ? 0x10000u : 1u;
            atomicAdd(&lh[b], add);
        }
    }
    __syncthreads();

    if (use_partials) {
        u32* mypart = partials + (size_t)blockIdx.x * ROWP;
        for (int b = threadIdx.x; b < NBINS; b += HIST_THREADS)
            mypart[b] = lh[b];
    } else {
        // fallback (ws too small): packed u64 global atomics into zeroed ghist
        for (int b = threadIdx.x; b < NBINS; b += HIST_THREADS) {
            u32 v = lh[b];
            if (v) {
                u64 a = ((u64)(v >> 16) << 32) | (u64)(v & 0xFFFFu);
                atomicAdd(&ghist[b], a);
            }
        }
    }
}

// ---------------------------------------------------------------------------
// Kernel 2 (fused reduce + scan): 240 blocks x 256 threads.
//   Phase A: block (c = bid%40, r = bid/40) sums PCHUNK rows for 256
//            consecutive bins (coalesced 1KB/row) -> packed u64 atomicAdd.
//   Ticket:  threadfence + atomicAdd(counter). The LAST block (ticket 239)
//            sees all ghist atomics complete and performs the exact integer
//            cumsum + KS max inline (device-scope atomic loads of ghist,
//            L2-hot), writing out[0]. Saves a kernel launch.
// ---------------------------------------------------------------------------
__global__ __launch_bounds__(256) void ks_reduce_scan(
        const u32* __restrict__ partials, u64* __restrict__ ghist,
        u32* __restrict__ counter, float* __restrict__ out) {
    __shared__ long long stp[256];
    __shared__ long long sfp[256];
    __shared__ double smx[256];
    __shared__ u32 s_ticket;

    const int t = threadIdx.x;
    const int col = blockIdx.x % RCOLS;
    const int row = blockIdx.x / RCOLS;
    const int bin = col * 256 + t;

    if (bin < NBINS) {
        const u32* base = partials + (size_t)row * PCHUNK * ROWP + bin;
        u32 tp = 0, fp = 0;
#pragma unroll 4
        for (int k = 0; k < PCHUNK; ++k) {
            u32 v = base[(size_t)k * ROWP];
            tp += v >> 16;
            fp += v & 0xFFFFu;
        }
        if (tp | fp) atomicAdd(&ghist[bin], ((u64)tp << 32) | (u64)fp);
    }

    __threadfence();
    if (t == 0) s_ticket = atomicAdd(counter, 1u);
    __syncthreads();
    if (s_ticket != RGRID - 1) return;

    // ---- scan phase (only the last-done block, 256 threads, 40 bins each) ----
    const int CH = 40;
    const int lo = t * CH;
    long long tps = 0, fps = 0;
    for (int k = 0; k < CH; ++k) {
        int i = lo + k;
        if (i < NBINS) {
            u64 v = __hip_atomic_load(&ghist[i], __ATOMIC_RELAXED,
                                      __HIP_MEMORY_SCOPE_AGENT);
            tps += (long long)(v >> 32);
            fps += (long long)(v & 0xFFFFFFFFull);
        }
    }
    stp[t] = tps;
    sfp[t] = fps;
    __syncthreads();

    for (int off = 1; off < 256; off <<= 1) {
        long long a = stp[t], b = sfp[t];
        long long c = 0, d = 0;
        if (t >= off) { c = stp[t - off]; d = sfp[t - off]; }
        __syncthreads();
        stp[t] = a + c;
        sfp[t] = b + d;
        __syncthreads();
    }

    const long long TP = stp[255];
    const long long FP = sfp[255];
    const double invTP = 1.0 / (double)(TP > 0 ? TP : 1);
    const double invFP = 1.0 / (double)(FP > 0 ? FP : 1);

    long long tc = stp[t] - tps;  // exclusive prefix
    long long fc = sfp[t] - fps;
    double m = 0.0;
    for (int k = 0; k < CH; ++k) {
        int i = lo + k;
        if (i < NBINS) {
            u64 v = __hip_atomic_load(&ghist[i], __ATOMIC_RELAXED,
                                      __HIP_MEMORY_SCOPE_AGENT);
            tc += (long long)(v >> 32);
            fc += (long long)(v & 0xFFFFFFFFull);
            double d = fabs((double)tc * invTP - (double)fc * invFP);
            m = (d > m) ? d : m;
        }
    }

    smx[t] = m;
    __syncthreads();
    for (int off = 128; off > 0; off >>= 1) {
        if (t < off) smx[t] = smx[t] > smx[t + off] ? smx[t] : smx[t + off];
        __syncthreads();
    }
    if (t == 0) out[0] = (float)smx[0];
}

// ---------------------------------------------------------------------------
// Kernel 3 (fallback only): standalone exact scan, 1 block x 1024 threads.
// ---------------------------------------------------------------------------
__global__ __launch_bounds__(1024) void ks_scan(const u64* __restrict__ ghist,
                                                float* __restrict__ out) {
    __shared__ long long stp[1024];
    __shared__ long long sfp[1024];
    __shared__ double smx[1024];

    const int t = threadIdx.x;
    const int CH = 10;
    const int lo = t * CH;

    u64 loc[CH];
    long long tps = 0, fps = 0;
#pragma unroll
    for (int k = 0; k < CH; ++k) {
        int i = lo + k;
        u64 v = (i < NBINS) ? ghist[i] : 0ull;
        loc[k] = v;
        tps += (long long)(v >> 32);
        fps += (long long)(v & 0xFFFFFFFFull);
    }
    stp[t] = tps;
    sfp[t] = fps;
    __syncthreads();

    for (int off = 1; off < 1024; off <<= 1) {
        long long a = stp[t], b = sfp[t];
        long long c = 0, d = 0;
        if (t >= off) { c = stp[t - off]; d = sfp[t - off]; }
        __syncthreads();
        stp[t] = a + c;
        sfp[t] = b + d;
        __syncthreads();
    }

    const long long TP = stp[1023];
    const long long FP = sfp[1023];
    const long long etp = stp[t] - tps;
    const long long efp = sfp[t] - fps;
    const double invTP = 1.0 / (double)(TP > 0 ? TP : 1);
    const double invFP = 1.0 / (double)(FP > 0 ? FP : 1);

    double m = 0.0;
    long long tc = etp, fc = efp;
#pragma unroll
    for (int k = 0; k < CH; ++k) {
        u64 v = loc[k];
        tc += (long long)(v >> 32);
        fc += (long long)(v & 0xFFFFFFFFull);
        double d = fabs((double)tc * invTP - (double)fc * invFP);
        m = (d > m) ? d : m;
    }

    smx[t] = m;
    __syncthreads();
    for (int off = 512; off > 0; off >>= 1) {
        if (t < off) smx[t] = smx[t] > smx[t + off] ? smx[t] : smx[t + off];
        __syncthreads();
    }
    if (t == 0) out[0] = (float)smx[0];
}

extern "C" void kernel_launch(void* const* d_in, const int* in_sizes, int n_in,
                              void* d_out, int out_size, void* d_ws, size_t ws_size,
                              hipStream_t stream) {
    const float* preds = (const float*)d_in[0];
    const float* tgts  = (const float*)d_in[1];
    const int n = in_sizes[0];

    // ws layout: [ghist: 10001 u64 (80008B)][counter u32 @80384]
    //            [partials @131072: HIST_BLOCKS x ROWP u32]
    const size_t ctr_off = 80384;
    const size_t part_off = 131072;
    const size_t need = part_off + (size_t)HIST_BLOCKS * ROWP * sizeof(u32);
    u64* ghist = (u64*)d_ws;
    u32* counter = (u32*)((char*)d_ws + ctr_off);
    u32* partials = (u32*)((char*)d_ws + part_off);
    const int use_partials = (ws_size >= need) ? 1 : 0;

    // zero ghist + ticket counter (80KB fill, ~1us)
    hipMemsetAsync(d_ws, 0, ctr_off + sizeof(u32), stream);

    ks_hist<<<HIST_BLOCKS, HIST_THREADS, 0, stream>>>(preds, tgts, ghist,
                                                      partials, use_partials, n);
    if (use_partials) {
        ks_reduce_scan<<<RGRID, 256, 0, stream>>>(partials, ghist, counter,
                                                  (float*)d_out);
    } else {
        ks_scan<<<1, 1024, 0, stream>>>(ghist, (float*)d_out);
    }
}

// Round 7
// 74.415 us; speedup vs baseline: 1.3322x; 1.3322x over previous
//
#include <hip/hip_runtime.h>

#define NBINS 10001
#define ROWP  10016          // padded row stride in u32 (64B-aligned rows)
#define HIST_BLOCKS 768      // 3 blocks/CU on 256 CUs -> one generation
#define HIST_THREADS 512
#define PCHUNK 128           // partial rows per reduce block

typedef unsigned int u32;
typedef unsigned long long u64;
typedef float f4 __attribute__((ext_vector_type(4)));

__device__ __forceinline__ int ks_bin(float x) {
    // sigmoid via v_exp + v_rcp (approx rcp ~1ulp; bin perturbation ~1e-7)
    float e = __expf(-x);
    float s = __builtin_amdgcn_rcpf(1.0f + e);
    int b = (int)(10000.0f * s);
    b = b < 0 ? 0 : b;
    return b > 10000 ? 10000 : b;
}

__device__ __forceinline__ void ks_acc4(u32* lh, f4 p, f4 t) {
#pragma unroll
    for (int k = 0; k < 4; ++k) {
        int b = ks_bin(p[k]);
        u32 add = (t[k] >= 0.5f) ? 0x10000u : 1u;
        atomicAdd(&lh[b], add);
    }
}

// ---------------------------------------------------------------------------
// Kernel 1: per-block LDS histogram (packed u32: tp<<16 | fp).
// Per block at most 45056 elements -> 16-bit packed counts cannot overflow.
// R3 structure (depth-2 rotation). Single change: targets are nontemporal
// (streaming array bypasses L1 allocation; preds stay cached / L3-resident).
// ---------------------------------------------------------------------------
__global__ __launch_bounds__(HIST_THREADS) void ks_hist(
        const float* __restrict__ preds, const float* __restrict__ tgts,
        u64* __restrict__ ghist, u32* __restrict__ partials,
        int use_partials, int n) {
    __shared__ u32 lh[NBINS];
    for (int i = threadIdx.x; i < NBINS; i += HIST_THREADS) lh[i] = 0u;
    __syncthreads();

    const int n4 = n >> 2;
    const f4* p4 = (const f4*)preds;
    const f4* t4 = (const f4*)tgts;
    const int tid = blockIdx.x * HIST_THREADS + threadIdx.x;
    const int stride = gridDim.x * HIST_THREADS;

    const int q = n4 / stride;
    const int r = n4 - q * stride;
    const int cnt = q + (tid < r ? 1 : 0);

    f4 pA, tA, pB, tB;
    if (cnt > 0) { pA = p4[tid]; tA = __builtin_nontemporal_load(t4 + tid); }
    if (cnt > 1) {
        pB = p4[tid + stride];
        tB = __builtin_nontemporal_load(t4 + tid + stride);
    }
    int idx = tid + stride;
    for (int k = 2; k < cnt; ++k) {
        idx += stride;
        f4 pC = p4[idx];
        f4 tC = __builtin_nontemporal_load(t4 + idx);
        ks_acc4(lh, pA, tA);
        pA = pB; tA = tB;
        pB = pC; tB = tC;
    }
    if (cnt > 1) {
        ks_acc4(lh, pA, tA);
        ks_acc4(lh, pB, tB);
    } else if (cnt == 1) {
        ks_acc4(lh, pA, tA);
    }

    // scalar tail (n % 4), handled once by block 0
    if (blockIdx.x == 0) {
        int base = n4 << 2;
        int rem = n - base;
        if ((int)threadIdx.x < rem) {
            int j = base + threadIdx.x;
            int b = ks_bin(preds[j]);
            u32 add = (tgts[j] >= 0.5f) ? 0x10000u : 1u;
            atomicAdd(&lh[b], add);
        }
    }
    __syncthreads();

    if (use_partials) {
        u32* mypart = partials + (size_t)blockIdx.x * ROWP;
        for (int b = threadIdx.x; b < NBINS; b += HIST_THREADS)
            mypart[b] = lh[b];
    } else {
        for (int b = threadIdx.x; b < NBINS; b += HIST_THREADS) {
            u32 v = lh[b];
            if (v) {
                u64 a = ((u64)(v >> 16) << 32) | (u64)(v & 0xFFFFu);
                atomicAdd(&ghist[b], a);
            }
        }
    }
}

// ---------------------------------------------------------------------------
// Kernel 2: reduce partial histograms. grid = (ceil(NBINS/256), HIST_BLOCKS/PCHUNK).
// Each block sums PCHUNK rows for 256 consecutive bins (coalesced 1KB/iter),
// then one packed-u64 atomic per bin per row-chunk.
// ---------------------------------------------------------------------------
__global__ __launch_bounds__(256) void ks_reduce(const u32* __restrict__ partials,
                                                 u64* __restrict__ ghist) {
    int bin = blockIdx.x * 256 + threadIdx.x;
    if (bin >= NBINS) return;
    const u32* base = partials + (size_t)blockIdx.y * PCHUNK * ROWP + bin;
    u32 tp = 0, fp = 0;
#pragma unroll 4
    for (int k = 0; k < PCHUNK; ++k) {
        u32 v = base[(size_t)k * ROWP];
        tp += v >> 16;
        fp += v & 0xFFFFu;
    }
    atomicAdd(&ghist[bin], ((u64)tp << 32) | (u64)fp);
}

// ---------------------------------------------------------------------------
// Kernel 3: exact integer cumsum over 10001 bins (1 block, 1024 threads,
// 10 bins/thread + Hillis-Steele block scan), KS diff in double, block max.
// ---------------------------------------------------------------------------
__global__ __launch_bounds__(1024) void ks_scan(const u64* __restrict__ ghist,
                                                float* __restrict__ out) {
    __shared__ long long stp[1024];
    __shared__ long long sfp[1024];
    __shared__ double smx[1024];

    const int t = threadIdx.x;
    const int CH = 10;  // 1024*10 >= 10001
    const int lo = t * CH;

    u64 loc[CH];
    long long tps = 0, fps = 0;
#pragma unroll
    for (int k = 0; k < CH; ++k) {
        int i = lo + k;
        u64 v = (i < NBINS) ? ghist[i] : 0ull;
        loc[k] = v;
        tps += (long long)(v >> 32);
        fps += (long long)(v & 0xFFFFFFFFull);
    }
    stp[t] = tps;
    sfp[t] = fps;
    __syncthreads();

    for (int off = 1; off < 1024; off <<= 1) {
        long long a = stp[t], b = sfp[t];
        long long c = 0, d = 0;
        if (t >= off) { c = stp[t - off]; d = sfp[t - off]; }
        __syncthreads();
        stp[t] = a + c;
        sfp[t] = b + d;
        __syncthreads();
    }

    const long long TP = stp[1023];
    const long long FP = sfp[1023];
    const long long etp = stp[t] - tps;  // exclusive prefix
    const long long efp = sfp[t] - fps;

    const double invTP = 1.0 / (double)(TP > 0 ? TP : 1);
    const double invFP = 1.0 / (double)(FP > 0 ? FP : 1);

    double m = 0.0;
    long long tc = etp, fc = efp;
#pragma unroll
    for (int k = 0; k < CH; ++k) {
        u64 v = loc[k];
        tc += (long long)(v >> 32);
        fc += (long long)(v & 0xFFFFFFFFull);
        double d = fabs((double)tc * invTP - (double)fc * invFP);
        m = (d > m) ? d : m;
    }

    smx[t] = m;
    __syncthreads();
    for (int off = 512; off > 0; off >>= 1) {
        if (t < off) smx[t] = smx[t] > smx[t + off] ? smx[t] : smx[t + off];
        __syncthreads();
    }
    if (t == 0) out[0] = (float)smx[0];
}

extern "C" void kernel_launch(void* const* d_in, const int* in_sizes, int n_in,
                              void* d_out, int out_size, void* d_ws, size_t ws_size,
                              hipStream_t stream) {
    const float* preds = (const float*)d_in[0];
    const float* tgts  = (const float*)d_in[1];
    const int n = in_sizes[0];

    // ws layout: [ghist: 10001 u64][pad to 128KB][partials: HIST_BLOCKS x ROWP u32]
    const size_t part_off = 131072;
    const size_t need = part_off + (size_t)HIST_BLOCKS * ROWP * sizeof(u32);
    u64* ghist = (u64*)d_ws;
    u32* partials = (u32*)((char*)d_ws + part_off);
    const int use_partials = (ws_size >= need) ? 1 : 0;

    hipMemsetAsync(d_ws, 0, NBINS * sizeof(u64), stream);

    ks_hist<<<HIST_BLOCKS, HIST_THREADS, 0, stream>>>(preds, tgts, ghist,
                                                      partials, use_partials, n);
    if (use_partials) {
        dim3 rg((NBINS + 255) / 256, HIST_BLOCKS / PCHUNK);
        ks_reduce<<<rg, 256, 0, stream>>>(partials, ghist);
    }
    ks_scan<<<1, 1024, 0, stream>>>(ghist, (float*)d_out);
}